// Round 21
// baseline (58.474 us; speedup 1.0000x reference)
//
#include <hip/hip_runtime.h>
#include <math.h>
#include <stdint.h>

#define D_MODEL 128
#define EDGE_DIM 9
#define HIDDEN 256
#define BATCH 2
#define NN 512

typedef _Float16 h2v    __attribute__((ext_vector_type(2)));
typedef __fp16   fp16x2 __attribute__((ext_vector_type(2)));
typedef _Float16 f16x8  __attribute__((ext_vector_type(8)));
typedef float    f32x4  __attribute__((ext_vector_type(4)));

struct H8 { h2v v[4]; };   // 16B = one MFMA A/B fragment

__device__ __forceinline__ uint32_t h2u(h2v v) { return __builtin_bit_cast(uint32_t, v); }
__device__ __forceinline__ h2v u2h(uint32_t u) { return __builtin_bit_cast(h2v, u); }
__device__ __forceinline__ h2v pkrtz(float a, float b) {
    return __builtin_bit_cast(h2v, __builtin_amdgcn_cvt_pkrtz(a, b));
}
__device__ __forceinline__ h2v relu2(h2v v) {
    h2v z = {(_Float16)0.0f, (_Float16)0.0f};
    return __builtin_elementwise_max(v, z);
}
__device__ __forceinline__ float fdot2(h2v a, h2v b, float c) {
    return __builtin_amdgcn_fdot2(__builtin_bit_cast(fp16x2, a),
                                  __builtin_bit_cast(fp16x2, b), c, false);
}
__device__ __forceinline__ float sigmoidf_(float x) { return 1.f / (1.f + expf(-x)); }
// uint4 element by unroll-constant index (folds to .x/.y/.z/.w)
__device__ __forceinline__ uint32_t el(const uint4& u, int k) {
    switch (k) { case 0: return u.x; case 1: return u.y; case 2: return u.z; default: return u.w; }
}

// ---------------------------------------------------------------------------
// Kernel 1 (MFMA): C = z @ W for one of {Wo1, We_i, We_j} per block.y.
// r18 version + block (rb==0, m==0) converts We_e/We2 to packed-f16 global
// workspace for the edge kernel's scalar-path weight reads.
// pj stored packed-group pj_q[hp>>2][row][hp&3].
// ---------------------------------------------------------------------------
__global__ __launch_bounds__(512) void node_mfma_kernel(
    const float* __restrict__ z,      // (B*N, 128)
    const float* __restrict__ Wo1,    // (128,256)
    const float* __restrict__ bo1,    // (256)
    const float* __restrict__ Wo2,    // (256,1)
    const float* __restrict__ bo2,    // (1)
    const float* __restrict__ We_i,   // (128,256)
    const float* __restrict__ We_j,   // (128,256)
    const float* __restrict__ be1,    // (256)
    const float* __restrict__ We_e,   // (9,256)
    const float* __restrict__ We2,    // (256,1)
    float* __restrict__ organ_out,    // (B*N)
    uint32_t* __restrict__ pi_h,      // (B*N,128) half2 rows, includes +be1
    uint32_t* __restrict__ pj_q,      // (32 groups,1024 rows) uint4-packed
    uint32_t* __restrict__ wee_g,     // (9*128) half2, [d][h2]
    uint32_t* __restrict__ we2_g)     // (128) half2
{
    __shared__ uint32_t Wlds[256][68];     // ~69.6 KiB, f16-pair, [h][d2^swz]
    __shared__ float org_part[32][4];

    const int t    = threadIdx.x;
    const int lane = t & 63;
    const int wave = t >> 6;
    const int rb   = blockIdx.x;           // row-block: rows 32*rb..32*rb+31
    const int m    = blockIdx.y;           // 0 = Wo1/organ, 1 = We_i/pi, 2 = We_j/pj

    const float* __restrict__ W = (m == 0) ? Wo1 : (m == 1) ? We_i : We_j;

    // ---- one block converts We_e/We2 to h2 workspace ----
    if (m == 0 && rb == 0) {
        for (int idx = t; idx < EDGE_DIM * 128; idx += 512) {
            const int d  = idx >> 7;
            const int h2 = idx & 127;
            wee_g[idx] = h2u(pkrtz(We_e[d * 256 + 2 * h2], We_e[d * 256 + 2 * h2 + 1]));
        }
        if (t < 128) we2_g[t] = h2u(pkrtz(We2[2 * t], We2[2 * t + 1]));
    }

    // ---- stage W -> LDS f16, transposed, swizzled ----
    for (int idx = t; idx < 64 * 256; idx += 512) {
        const int d2 = idx >> 8;           // 0..63 (d-pair)
        const int h  = idx & 255;          // coalesced over h
        const float wlo = W[(2 * d2) * 256 + h];
        const float whi = W[(2 * d2 + 1) * 256 + h];
        Wlds[h][d2 ^ ((h & 7) << 3)] = h2u(pkrtz(wlo, whi));
    }

    // ---- A-frags straight from global ----
    const int rt = wave & 1;               // row-tile
    const int cg = wave >> 1;              // col-group (4 tiles of 16)
    const int kg = lane >> 4;              // k-subgroup
    const int row = rb * 32 + rt * 16 + (lane & 15);

    f16x8 A[4];
#pragma unroll
    for (int kt = 0; kt < 4; ++kt) {
        const float4 za = *(const float4*)&z[(size_t)row * 128 + kt * 32 + kg * 8];
        const float4 zb = *(const float4*)&z[(size_t)row * 128 + kt * 32 + kg * 8 + 4];
        H8 a;
        a.v[0] = pkrtz(za.x, za.y); a.v[1] = pkrtz(za.z, za.w);
        a.v[2] = pkrtz(zb.x, zb.y); a.v[3] = pkrtz(zb.z, zb.w);
        A[kt] = __builtin_bit_cast(f16x8, a);
    }

    __syncthreads();

    // ---- MFMA main: 4 col-tiles x 4 k-tiles ----
    f32x4 C[4];
#pragma unroll
    for (int ct = 0; ct < 4; ++ct) {
        const int col = (cg * 4 + ct) * 16 + (lane & 15);
        C[ct] = (f32x4){0.f, 0.f, 0.f, 0.f};
#pragma unroll
        for (int kt = 0; kt < 4; ++kt) {
            const int d2b = (kt * 16 + kg * 4) ^ ((col & 7) << 3);
            const uint4 w = *(const uint4*)&Wlds[col][d2b];
            H8 b;
            b.v[0] = u2h(w.x); b.v[1] = u2h(w.y);
            b.v[2] = u2h(w.z); b.v[3] = u2h(w.w);
            C[ct] = __builtin_amdgcn_mfma_f32_16x16x32_f16(
                        A[kt], __builtin_bit_cast(f16x8, b), C[ct], 0, 0, 0);
        }
    }

    // ---- epilogues ----
    if (m == 0) {
        float s0 = 0.f, s1 = 0.f, s2 = 0.f, s3 = 0.f;
#pragma unroll
        for (int ct = 0; ct < 4; ++ct) {
            const int col = (cg * 4 + ct) * 16 + (lane & 15);
            const float b1 = bo1[col];
            const float w2 = Wo2[col];
            s0 = fmaf(fmaxf(C[ct].x + b1, 0.f), w2, s0);
            s1 = fmaf(fmaxf(C[ct].y + b1, 0.f), w2, s1);
            s2 = fmaf(fmaxf(C[ct].z + b1, 0.f), w2, s2);
            s3 = fmaf(fmaxf(C[ct].w + b1, 0.f), w2, s3);
        }
#pragma unroll
        for (int off = 1; off <= 8; off <<= 1) {
            s0 += __shfl_xor(s0, off, 64);
            s1 += __shfl_xor(s1, off, 64);
            s2 += __shfl_xor(s2, off, 64);
            s3 += __shfl_xor(s3, off, 64);
        }
        if ((lane & 15) == 0) {
            const int rbase = rt * 16 + kg * 4;
            org_part[rbase + 0][cg] = s0;
            org_part[rbase + 1][cg] = s1;
            org_part[rbase + 2][cg] = s2;
            org_part[rbase + 3][cg] = s3;
        }
        __syncthreads();
        if (t < 32) {
            const float s = org_part[t][0] + org_part[t][1]
                          + org_part[t][2] + org_part[t][3] + bo2[0];
            organ_out[rb * 32 + t] = sigmoidf_(s);
        }
    } else if (m == 1) {
        // pi: row-major [row][hp], +be1
#pragma unroll
        for (int ct = 0; ct < 4; ++ct) {
            const int col = (cg * 4 + ct) * 16 + (lane & 15);
            const float bv = be1[col];
            float v0 = C[ct].x + bv, v1 = C[ct].y + bv;
            float v2 = C[ct].z + bv, v3 = C[ct].w + bv;
            const float p0 = __shfl_xor(v0, 1, 64);
            const float p1 = __shfl_xor(v1, 1, 64);
            const float p2 = __shfl_xor(v2, 1, 64);
            const float p3 = __shfl_xor(v3, 1, 64);
            if (!(lane & 1)) {
                const int hp = col >> 1;
                const size_t gr = (size_t)(rb * 32 + rt * 16 + kg * 4);
                pi_h[(gr + 0) * 128 + hp] = h2u(pkrtz(v0, p0));
                pi_h[(gr + 1) * 128 + hp] = h2u(pkrtz(v1, p1));
                pi_h[(gr + 2) * 128 + hp] = h2u(pkrtz(v2, p2));
                pi_h[(gr + 3) * 128 + hp] = h2u(pkrtz(v3, p3));
            }
        }
    } else {
        // pj: packed-group layout [hp>>2][row][hp&3]
#pragma unroll
        for (int ct = 0; ct < 4; ++ct) {
            const int col = (cg * 4 + ct) * 16 + (lane & 15);
            float v0 = C[ct].x, v1 = C[ct].y, v2 = C[ct].z, v3 = C[ct].w;
            const float p0 = __shfl_xor(v0, 1, 64);
            const float p1 = __shfl_xor(v1, 1, 64);
            const float p2 = __shfl_xor(v2, 1, 64);
            const float p3 = __shfl_xor(v3, 1, 64);
            if (!(lane & 1)) {
                const int hp = col >> 1;
                const size_t gr = (size_t)(rb * 32 + rt * 16 + kg * 4);
                const size_t gbase = (size_t)(hp >> 2) * 1024;
                const int    sub   = hp & 3;
                pj_q[(gbase + gr + 0) * 4 + sub] = h2u(pkrtz(v0, p0));
                pj_q[(gbase + gr + 1) * 4 + sub] = h2u(pkrtz(v1, p1));
                pj_q[(gbase + gr + 2) * 4 + sub] = h2u(pkrtz(v2, p2));
                pj_q[(gbase + gr + 3) * 4 + sub] = h2u(pkrtz(v3, p3));
            }
        }
    }
}

// ---------------------------------------------------------------------------
// Kernel 2: fused edge head — r20 (h-split, 8 waves/SIMD, wide pj) +
// WEIGHTS OFF THE LDS PIPE.
// Bottleneck audit (r20): 12 ds_read_b128/iter x ~12cy on the shared per-CU
// LDS pipe = 1.57M reads -> ~30.7 us, matching measured edge time across
// r15-r20 exactly; occupancy/prefetch changes couldn't move it. Weights
// (10 of 12 reads, wave-uniform, block-invariant) now come from packed-f16
// GLOBAL workspace with a uniform index on a __restrict__ arg -> scalar
// s_load path (or 1-line L1 vector hits). Per-iter pipe load becomes:
// LDS 2 instr (pi), VMEM <=12, VALU 136 cy -> VALU-bound at last.
// ---------------------------------------------------------------------------
__global__ __launch_bounds__(256) void edge_kernel(
    const float* __restrict__ E,      // (N,N,9)
    const int*   __restrict__ mask,   // (N,N)
    const uint32_t* __restrict__ wee_g, // (9*128) half2, [d][h2]
    const uint32_t* __restrict__ we2_g, // (128) half2
    const float* __restrict__ be2,    // (1)
    const uint32_t* __restrict__ pi_h,  // (B*N,128) half2 rows
    const uint32_t* __restrict__ pj_q,  // (32,1024) uint4-packed
    float* __restrict__ edge_out)     // (B,N,N)
{
    __shared__ __align__(16) uint32_t pi_s[BATCH][4][128];  // 4 KiB
    __shared__ __align__(16) float    part_s[4][32][2];     // 1 KiB

    const int t    = threadIdx.x;
    const int lane = t & 63;
    const int w    = t >> 6;           // wave: (hh = w>>1, ip = w&1)
    const int bi   = blockIdx.x;
    const int i0   = (bi >> 4) * 4;    // 128 i-blocks
    const int j0   = (bi & 15) * 32;   // 16 j-blocks

    const int jl = lane & 31;
    const int il = 2 * (w & 1) + (lane >> 5);  // local i row 0..3
    const int hh = w >> 1;                     // h-half 0/1

    // ---- stage pi rows: 2 b x 4 i x 128 words = 256 uint4, 1/thread ----
    {
        const int r8 = t >> 5;                // 0..7
        const int c4 = t & 31;                // uint4 col
        const int b  = r8 >> 2;
        const int ii = r8 & 3;
        const uint4 v = *(const uint4*)&pi_h[(size_t)(b * NN + i0 + ii) * 128 + c4 * 4];
        *(uint4*)&pi_s[b][ii][c4 * 4] = v;
    }

    // ---- direct per-lane E registers: 9 floats, stride-36B coalesced ----
    h2v e[9];
    {
        const float* eptr = &E[((size_t)(i0 + il) * NN + j0 + jl) * EDGE_DIM];
        float ef[9];
#pragma unroll
        for (int d = 0; d < EDGE_DIM; ++d) ef[d] = eptr[d];
#pragma unroll
        for (int d = 0; d < EDGE_DIM; ++d) e[d] = pkrtz(ef[d], ef[d]);
    }

    __syncthreads();

    float acc[2] = {0.f, 0.f};   // [b]

    const uint4* __restrict__ pjQ   = (const uint4*)pj_q;   // [32][1024]
    const uint4* __restrict__ weeQ  = (const uint4*)wee_g;  // [9][32]
    const uint4* __restrict__ we2Q  = (const uint4*)we2_g;  // [32]
    const int jrow = j0 + jl;
    const int g0   = hh * 16;    // this wave's 16 h-groups

#pragma unroll 1
    for (int gg = 0; gg < 16; ++gg) {
        const int g  = g0 + gg;
        const int hc = g * 4;
        // weights: wave-uniform index on __restrict__ global -> scalar path
        uint4 wee4[EDGE_DIM];
#pragma unroll
        for (int d = 0; d < EDGE_DIM; ++d) wee4[d] = weeQ[d * 32 + g];
        const uint4 we24 = we2Q[g];
        // pi (LDS, 2-way broadcast across lane halves)
        uint4 pi4[2];
        pi4[0] = *(const uint4*)&pi_s[0][il][hc];
        pi4[1] = *(const uint4*)&pi_s[1][il][hc];
        // pj: ONE b128 per batch (512B contiguous per half-wave)
        const uint4 pj40 = pjQ[g * 1024 + jrow];          // b = 0
        const uint4 pj41 = pjQ[g * 1024 + NN + jrow];     // b = 1

#pragma unroll
        for (int k = 0; k < 4; ++k) {
            const h2v w2k = u2h(el(we24, k));
            h2v pe = e[0] * u2h(el(wee4[0], k));
#pragma unroll
            for (int d = 1; d < EDGE_DIM; ++d) pe += e[d] * u2h(el(wee4[d], k));
            h2v t0 = relu2(pe + u2h(el(pj40, k)) + u2h(el(pi4[0], k)));
            acc[0] = fdot2(t0, w2k, acc[0]);
            h2v t1 = relu2(pe + u2h(el(pj41, k)) + u2h(el(pi4[1], k)));
            acc[1] = fdot2(t1, w2k, acc[1]);
        }
    }

    // ---- combine h-halves via LDS; hh=0 waves finish ----
    if (hh == 1) {
        part_s[il][jl][0] = acc[0];
        part_s[il][jl][1] = acc[1];
    }
    __syncthreads();
    if (hh == 0) {
        const float b2 = be2[0];
        const int i = i0 + il;
        const float mv = (float)mask[(size_t)i * NN + j0 + jl];
        const float s0 = acc[0] + part_s[il][jl][0] + b2;
        const float s1 = acc[1] + part_s[il][jl][1] + b2;
        edge_out[((size_t)0 * NN + i) * NN + j0 + jl] = sigmoidf_(s0) * mv;
        edge_out[((size_t)1 * NN + i) * NN + j0 + jl] = sigmoidf_(s1) * mv;
    }
}

extern "C" void kernel_launch(void* const* d_in, const int* in_sizes, int n_in,
                              void* d_out, int out_size, void* d_ws, size_t ws_size,
                              hipStream_t stream) {
    const float* z    = (const float*)d_in[0];   // (B,N,128)
    const float* E    = (const float*)d_in[1];   // (N,N,9)
    const int*   mask = (const int*)  d_in[2];   // (N,N)
    const float* Wo1  = (const float*)d_in[3];
    const float* bo1  = (const float*)d_in[4];
    const float* Wo2  = (const float*)d_in[5];
    const float* bo2  = (const float*)d_in[6];
    const float* We_i = (const float*)d_in[7];
    const float* We_j = (const float*)d_in[8];
    const float* We_e = (const float*)d_in[9];
    const float* be1  = (const float*)d_in[10];
    const float* We2  = (const float*)d_in[11];
    const float* be2  = (const float*)d_in[12];

    float* out_organ = (float*)d_out;                 // (B,N) = 1024
    float* out_edge  = out_organ + BATCH * NN;        // (B,N,N)

    uint32_t* pi_h  = (uint32_t*)d_ws;                        // (B*N,128) half2
    uint32_t* pj_q  = pi_h + (size_t)BATCH * NN * (HIDDEN/2); // (32,1024) uint4-packed
    uint32_t* wee_g = pj_q + (size_t)BATCH * NN * (HIDDEN/2); // (9*128) half2
    uint32_t* we2_g = wee_g + EDGE_DIM * 128;                 // (128) half2

    hipLaunchKernelGGL(node_mfma_kernel,
                       dim3(32, 3), dim3(512), 0, stream,
                       z, Wo1, bo1, Wo2, bo2, We_i, We_j, be1, We_e, We2,
                       out_organ, pi_h, pj_q, wee_g, we2_g);

    hipLaunchKernelGGL(edge_kernel,
                       dim3(128 * 16), dim3(256), 0, stream,
                       E, mask, wee_g, we2_g, be2, pi_h, pj_q, out_edge);
}

// Round 22
// 36.750 us; speedup vs baseline: 1.5911x; 1.5911x over previous
//
#include <hip/hip_runtime.h>
#include <math.h>
#include <stdint.h>

#define D_MODEL 128
#define EDGE_DIM 9
#define HIDDEN 256
#define BATCH 2
#define NN 512

typedef _Float16 h2v    __attribute__((ext_vector_type(2)));
typedef __fp16   fp16x2 __attribute__((ext_vector_type(2)));
typedef _Float16 f16x8  __attribute__((ext_vector_type(8)));
typedef float    f32x4  __attribute__((ext_vector_type(4)));

struct H8 { h2v v[4]; };   // 16B = one MFMA A/B fragment

__device__ __forceinline__ uint32_t h2u(h2v v) { return __builtin_bit_cast(uint32_t, v); }
__device__ __forceinline__ h2v u2h(uint32_t u) { return __builtin_bit_cast(h2v, u); }
__device__ __forceinline__ h2v pkrtz(float a, float b) {
    return __builtin_bit_cast(h2v, __builtin_amdgcn_cvt_pkrtz(a, b));
}
__device__ __forceinline__ h2v relu2(h2v v) {
    h2v z = {(_Float16)0.0f, (_Float16)0.0f};
    return __builtin_elementwise_max(v, z);
}
__device__ __forceinline__ float fdot2(h2v a, h2v b, float c) {
    return __builtin_amdgcn_fdot2(__builtin_bit_cast(fp16x2, a),
                                  __builtin_bit_cast(fp16x2, b), c, false);
}
__device__ __forceinline__ float sigmoidf_(float x) { return 1.f / (1.f + expf(-x)); }
// uint4 element by unroll-constant index (folds to .x/.y/.z/.w)
__device__ __forceinline__ uint32_t el(const uint4& u, int k) {
    switch (k) { case 0: return u.x; case 1: return u.y; case 2: return u.z; default: return u.w; }
}

// ---------------------------------------------------------------------------
// Kernel 1 (MFMA): C = z @ W for one of {Wo1, We_i, We_j} per block.y.
// (Identical to round 20: pj stored packed-group pj_q[hp>>2][row][hp&3].)
// ---------------------------------------------------------------------------
__global__ __launch_bounds__(512) void node_mfma_kernel(
    const float* __restrict__ z,      // (B*N, 128)
    const float* __restrict__ Wo1,    // (128,256)
    const float* __restrict__ bo1,    // (256)
    const float* __restrict__ Wo2,    // (256,1)
    const float* __restrict__ bo2,    // (1)
    const float* __restrict__ We_i,   // (128,256)
    const float* __restrict__ We_j,   // (128,256)
    const float* __restrict__ be1,    // (256)
    float* __restrict__ organ_out,    // (B*N)
    uint32_t* __restrict__ pi_h,      // (B*N,128) half2 rows, includes +be1
    uint32_t* __restrict__ pj_q)      // (32 groups,1024 rows) uint4-packed
{
    __shared__ uint32_t Wlds[256][68];     // ~69.6 KiB, f16-pair, [h][d2^swz]
    __shared__ float org_part[32][4];

    const int t    = threadIdx.x;
    const int lane = t & 63;
    const int wave = t >> 6;
    const int rb   = blockIdx.x;           // row-block: rows 32*rb..32*rb+31
    const int m    = blockIdx.y;           // 0 = Wo1/organ, 1 = We_i/pi, 2 = We_j/pj

    const float* __restrict__ W = (m == 0) ? Wo1 : (m == 1) ? We_i : We_j;

    // ---- stage W -> LDS f16, transposed, swizzled ----
    for (int idx = t; idx < 64 * 256; idx += 512) {
        const int d2 = idx >> 8;           // 0..63 (d-pair)
        const int h  = idx & 255;          // coalesced over h
        const float wlo = W[(2 * d2) * 256 + h];
        const float whi = W[(2 * d2 + 1) * 256 + h];
        Wlds[h][d2 ^ ((h & 7) << 3)] = h2u(pkrtz(wlo, whi));
    }

    // ---- A-frags straight from global ----
    const int rt = wave & 1;               // row-tile
    const int cg = wave >> 1;              // col-group (4 tiles of 16)
    const int kg = lane >> 4;              // k-subgroup
    const int row = rb * 32 + rt * 16 + (lane & 15);

    f16x8 A[4];
#pragma unroll
    for (int kt = 0; kt < 4; ++kt) {
        const float4 za = *(const float4*)&z[(size_t)row * 128 + kt * 32 + kg * 8];
        const float4 zb = *(const float4*)&z[(size_t)row * 128 + kt * 32 + kg * 8 + 4];
        H8 a;
        a.v[0] = pkrtz(za.x, za.y); a.v[1] = pkrtz(za.z, za.w);
        a.v[2] = pkrtz(zb.x, zb.y); a.v[3] = pkrtz(zb.z, zb.w);
        A[kt] = __builtin_bit_cast(f16x8, a);
    }

    __syncthreads();

    // ---- MFMA main: 4 col-tiles x 4 k-tiles ----
    f32x4 C[4];
#pragma unroll
    for (int ct = 0; ct < 4; ++ct) {
        const int col = (cg * 4 + ct) * 16 + (lane & 15);
        C[ct] = (f32x4){0.f, 0.f, 0.f, 0.f};
#pragma unroll
        for (int kt = 0; kt < 4; ++kt) {
            const int d2b = (kt * 16 + kg * 4) ^ ((col & 7) << 3);
            const uint4 w = *(const uint4*)&Wlds[col][d2b];
            H8 b;
            b.v[0] = u2h(w.x); b.v[1] = u2h(w.y);
            b.v[2] = u2h(w.z); b.v[3] = u2h(w.w);
            C[ct] = __builtin_amdgcn_mfma_f32_16x16x32_f16(
                        A[kt], __builtin_bit_cast(f16x8, b), C[ct], 0, 0, 0);
        }
    }

    // ---- epilogues ----
    if (m == 0) {
        float s0 = 0.f, s1 = 0.f, s2 = 0.f, s3 = 0.f;
#pragma unroll
        for (int ct = 0; ct < 4; ++ct) {
            const int col = (cg * 4 + ct) * 16 + (lane & 15);
            const float b1 = bo1[col];
            const float w2 = Wo2[col];
            s0 = fmaf(fmaxf(C[ct].x + b1, 0.f), w2, s0);
            s1 = fmaf(fmaxf(C[ct].y + b1, 0.f), w2, s1);
            s2 = fmaf(fmaxf(C[ct].z + b1, 0.f), w2, s2);
            s3 = fmaf(fmaxf(C[ct].w + b1, 0.f), w2, s3);
        }
#pragma unroll
        for (int off = 1; off <= 8; off <<= 1) {
            s0 += __shfl_xor(s0, off, 64);
            s1 += __shfl_xor(s1, off, 64);
            s2 += __shfl_xor(s2, off, 64);
            s3 += __shfl_xor(s3, off, 64);
        }
        if ((lane & 15) == 0) {
            const int rbase = rt * 16 + kg * 4;
            org_part[rbase + 0][cg] = s0;
            org_part[rbase + 1][cg] = s1;
            org_part[rbase + 2][cg] = s2;
            org_part[rbase + 3][cg] = s3;
        }
        __syncthreads();
        if (t < 32) {
            const float s = org_part[t][0] + org_part[t][1]
                          + org_part[t][2] + org_part[t][3] + bo2[0];
            organ_out[rb * 32 + t] = sigmoidf_(s);
        }
    } else if (m == 1) {
        // pi: row-major [row][hp], +be1
#pragma unroll
        for (int ct = 0; ct < 4; ++ct) {
            const int col = (cg * 4 + ct) * 16 + (lane & 15);
            const float bv = be1[col];
            float v0 = C[ct].x + bv, v1 = C[ct].y + bv;
            float v2 = C[ct].z + bv, v3 = C[ct].w + bv;
            const float p0 = __shfl_xor(v0, 1, 64);
            const float p1 = __shfl_xor(v1, 1, 64);
            const float p2 = __shfl_xor(v2, 1, 64);
            const float p3 = __shfl_xor(v3, 1, 64);
            if (!(lane & 1)) {
                const int hp = col >> 1;
                const size_t gr = (size_t)(rb * 32 + rt * 16 + kg * 4);
                pi_h[(gr + 0) * 128 + hp] = h2u(pkrtz(v0, p0));
                pi_h[(gr + 1) * 128 + hp] = h2u(pkrtz(v1, p1));
                pi_h[(gr + 2) * 128 + hp] = h2u(pkrtz(v2, p2));
                pi_h[(gr + 3) * 128 + hp] = h2u(pkrtz(v3, p3));
            }
        }
    } else {
        // pj: packed-group layout [hp>>2][row][hp&3]
#pragma unroll
        for (int ct = 0; ct < 4; ++ct) {
            const int col = (cg * 4 + ct) * 16 + (lane & 15);
            float v0 = C[ct].x, v1 = C[ct].y, v2 = C[ct].z, v3 = C[ct].w;
            const float p0 = __shfl_xor(v0, 1, 64);
            const float p1 = __shfl_xor(v1, 1, 64);
            const float p2 = __shfl_xor(v2, 1, 64);
            const float p3 = __shfl_xor(v3, 1, 64);
            if (!(lane & 1)) {
                const int hp = col >> 1;
                const size_t gr = (size_t)(rb * 32 + rt * 16 + kg * 4);
                const size_t gbase = (size_t)(hp >> 2) * 1024;
                const int    sub   = hp & 3;
                pj_q[(gbase + gr + 0) * 4 + sub] = h2u(pkrtz(v0, p0));
                pj_q[(gbase + gr + 1) * 4 + sub] = h2u(pkrtz(v1, p1));
                pj_q[(gbase + gr + 2) * 4 + sub] = h2u(pkrtz(v2, p2));
                pj_q[(gbase + gr + 3) * 4 + sub] = h2u(pkrtz(v3, p3));
            }
        }
    }
}

// ---------------------------------------------------------------------------
// Kernel 2: fused edge head — r20 (h-split, wide pj, LDS weights) with
// 2-J-PER-LANE amortization of the LDS-read wall.
// Validated model: edge time == LDS-read wall (wave-iters x 12 reads x 12cy
// / 256 CU = 30.7us in r20; r21's weights-to-global attempt regressed: the
// compiler can't prove wave-uniformity -> per-lane VMEM, 51us). Fix: each
// lane computes jA=j0+jl and jB=j0+32+jl (tile 4i x 64j, grid unchanged at
// 1024 blocks). The 10 weight reads/iter now feed 4 accumulators instead
// of 2 -> wave-iterations halve -> LDS wall ~15.4us; VALU wall ~7.2us;
// pj = 4 b128 VMEM/iter (trivial TA load). unroll 1 retained (anti-spill).
// ---------------------------------------------------------------------------
__global__ __launch_bounds__(256) void edge_kernel(
    const float* __restrict__ E,      // (N,N,9)
    const int*   __restrict__ mask,   // (N,N)
    const float* __restrict__ We_e,   // (9,256)
    const float* __restrict__ We2,    // (256,1)
    const float* __restrict__ be2,    // (1)
    const uint32_t* __restrict__ pi_h,  // (B*N,128) half2 rows
    const uint32_t* __restrict__ pj_q,  // (32,1024) uint4-packed
    float* __restrict__ edge_out)     // (B,N,N)
{
    __shared__ __align__(16) uint32_t wee_s[EDGE_DIM][128]; // 4.5 KiB
    __shared__ __align__(16) uint32_t we2_s[128];           // 0.5 KiB
    __shared__ __align__(16) uint32_t pi_s[BATCH][4][128];  // 4 KiB
    __shared__ __align__(16) float    part_s[4][64][2];     // 2 KiB

    const int t    = threadIdx.x;
    const int lane = t & 63;
    const int w    = t >> 6;           // wave: (hh = w>>1, ip = w&1)
    const int bi   = blockIdx.x;
    const int i0   = (bi >> 3) * 4;    // 128 i-blocks
    const int j0   = (bi & 7) * 64;    // 8 j-blocks

    const int jl = lane & 31;
    const int il = 2 * (w & 1) + (lane >> 5);  // local i row 0..3
    const int hh = w >> 1;                     // h-half 0/1

    // ---- stage We_e as h2v [d][h2] ----
    for (int idx = t; idx < EDGE_DIM * 128; idx += 256) {
        const int d  = idx >> 7;
        const int h2 = idx & 127;
        wee_s[d][h2] = h2u(pkrtz(We_e[d * 256 + 2 * h2], We_e[d * 256 + 2 * h2 + 1]));
    }
    // ---- stage We2 as h2v ----
    if (t < 128) we2_s[t] = h2u(pkrtz(We2[2 * t], We2[2 * t + 1]));
    // ---- stage pi rows: 2 b x 4 i x 128 words = 256 uint4, 1/thread ----
    {
        const int r8 = t >> 5;                // 0..7
        const int c4 = t & 31;                // uint4 col
        const int b  = r8 >> 2;
        const int ii = r8 & 3;
        const uint4 v = *(const uint4*)&pi_h[(size_t)(b * NN + i0 + ii) * 128 + c4 * 4];
        *(uint4*)&pi_s[b][ii][c4 * 4] = v;
    }

    // ---- direct per-lane E registers for BOTH j's ----
    h2v eA[9], eB[9];
    {
        const float* ea = &E[((size_t)(i0 + il) * NN + j0 + jl) * EDGE_DIM];
        const float* eb = &E[((size_t)(i0 + il) * NN + j0 + 32 + jl) * EDGE_DIM];
#pragma unroll
        for (int d = 0; d < EDGE_DIM; ++d) eA[d] = pkrtz(ea[d], ea[d]);
#pragma unroll
        for (int d = 0; d < EDGE_DIM; ++d) eB[d] = pkrtz(eb[d], eb[d]);
    }

    __syncthreads();

    float accA[2] = {0.f, 0.f};   // jA, [b]
    float accB[2] = {0.f, 0.f};   // jB, [b]

    const uint4* __restrict__ pjQ = (const uint4*)pj_q;   // [32][1024]
    const int jA = j0 + jl;
    const int jB = j0 + 32 + jl;
    const int g0 = hh * 16;       // this wave's 16 h-groups

#pragma unroll 1
    for (int gg = 0; gg < 16; ++gg) {
        const int g  = g0 + gg;
        const int hc = g * 4;
        // broadcast weights (LDS, wave-uniform address) — 10 reads / iter
        uint4 wee4[EDGE_DIM];
#pragma unroll
        for (int d = 0; d < EDGE_DIM; ++d) wee4[d] = *(const uint4*)&wee_s[d][hc];
        const uint4 we24 = *(const uint4*)&we2_s[hc];
        // pi (LDS, 2 reads; shared by jA and jB)
        uint4 pi4[2];
        pi4[0] = *(const uint4*)&pi_s[0][il][hc];
        pi4[1] = *(const uint4*)&pi_s[1][il][hc];
        // pj: 4 b128 VMEM (coalesced 512B per half-wave)
        const uint4 pjA0 = pjQ[g * 1024 + jA];
        const uint4 pjA1 = pjQ[g * 1024 + NN + jA];
        const uint4 pjB0 = pjQ[g * 1024 + jB];
        const uint4 pjB1 = pjQ[g * 1024 + NN + jB];

#pragma unroll
        for (int k = 0; k < 4; ++k) {
            const h2v w2k = u2h(el(we24, k));
            const h2v piv0 = u2h(el(pi4[0], k));
            const h2v piv1 = u2h(el(pi4[1], k));
            h2v peA = eA[0] * u2h(el(wee4[0], k));
            h2v peB = eB[0] * u2h(el(wee4[0], k));
#pragma unroll
            for (int d = 1; d < EDGE_DIM; ++d) {
                const h2v wd = u2h(el(wee4[d], k));
                peA += eA[d] * wd;
                peB += eB[d] * wd;
            }
            accA[0] = fdot2(relu2(peA + u2h(el(pjA0, k)) + piv0), w2k, accA[0]);
            accA[1] = fdot2(relu2(peA + u2h(el(pjA1, k)) + piv1), w2k, accA[1]);
            accB[0] = fdot2(relu2(peB + u2h(el(pjB0, k)) + piv0), w2k, accB[0]);
            accB[1] = fdot2(relu2(peB + u2h(el(pjB1, k)) + piv1), w2k, accB[1]);
        }
    }

    // ---- combine h-halves via LDS; hh=0 waves finish ----
    if (hh == 1) {
        part_s[il][jl][0]      = accA[0];
        part_s[il][jl][1]      = accA[1];
        part_s[il][jl + 32][0] = accB[0];
        part_s[il][jl + 32][1] = accB[1];
    }
    __syncthreads();
    if (hh == 0) {
        const float b2 = be2[0];
        const int i = i0 + il;
        const float mvA = (float)mask[(size_t)i * NN + jA];
        const float mvB = (float)mask[(size_t)i * NN + jB];
        const float sA0 = accA[0] + part_s[il][jl][0] + b2;
        const float sA1 = accA[1] + part_s[il][jl][1] + b2;
        const float sB0 = accB[0] + part_s[il][jl + 32][0] + b2;
        const float sB1 = accB[1] + part_s[il][jl + 32][1] + b2;
        edge_out[((size_t)0 * NN + i) * NN + jA] = sigmoidf_(sA0) * mvA;
        edge_out[((size_t)1 * NN + i) * NN + jA] = sigmoidf_(sA1) * mvA;
        edge_out[((size_t)0 * NN + i) * NN + jB] = sigmoidf_(sB0) * mvB;
        edge_out[((size_t)1 * NN + i) * NN + jB] = sigmoidf_(sB1) * mvB;
    }
}

extern "C" void kernel_launch(void* const* d_in, const int* in_sizes, int n_in,
                              void* d_out, int out_size, void* d_ws, size_t ws_size,
                              hipStream_t stream) {
    const float* z    = (const float*)d_in[0];   // (B,N,128)
    const float* E    = (const float*)d_in[1];   // (N,N,9)
    const int*   mask = (const int*)  d_in[2];   // (N,N)
    const float* Wo1  = (const float*)d_in[3];
    const float* bo1  = (const float*)d_in[4];
    const float* Wo2  = (const float*)d_in[5];
    const float* bo2  = (const float*)d_in[6];
    const float* We_i = (const float*)d_in[7];
    const float* We_j = (const float*)d_in[8];
    const float* We_e = (const float*)d_in[9];
    const float* be1  = (const float*)d_in[10];
    const float* We2  = (const float*)d_in[11];
    const float* be2  = (const float*)d_in[12];

    float* out_organ = (float*)d_out;                 // (B,N) = 1024
    float* out_edge  = out_organ + BATCH * NN;        // (B,N,N)

    uint32_t* pi_h = (uint32_t*)d_ws;                        // (B*N,128) half2
    uint32_t* pj_q = pi_h + (size_t)BATCH * NN * (HIDDEN/2); // (32,1024) uint4-packed

    hipLaunchKernelGGL(node_mfma_kernel,
                       dim3(32, 3), dim3(512), 0, stream,
                       z, Wo1, bo1, Wo2, bo2, We_i, We_j, be1,
                       out_organ, pi_h, pj_q);

    hipLaunchKernelGGL(edge_kernel,
                       dim3(128 * 8), dim3(256), 0, stream,
                       E, mask, We_e, We2, be2, pi_h, pj_q, out_edge);
}

// Round 23
// 34.280 us; speedup vs baseline: 1.7058x; 1.0720x over previous
//
#include <hip/hip_runtime.h>
#include <math.h>
#include <stdint.h>

#define D_MODEL 128
#define EDGE_DIM 9
#define HIDDEN 256
#define BATCH 2
#define NN 512

typedef _Float16 h2v    __attribute__((ext_vector_type(2)));
typedef __fp16   fp16x2 __attribute__((ext_vector_type(2)));
typedef _Float16 f16x8  __attribute__((ext_vector_type(8)));
typedef float    f32x4  __attribute__((ext_vector_type(4)));

struct H8 { h2v v[4]; };   // 16B = one MFMA A/B fragment

__device__ __forceinline__ uint32_t h2u(h2v v) { return __builtin_bit_cast(uint32_t, v); }
__device__ __forceinline__ h2v u2h(uint32_t u) { return __builtin_bit_cast(h2v, u); }
__device__ __forceinline__ h2v pkrtz(float a, float b) {
    return __builtin_bit_cast(h2v, __builtin_amdgcn_cvt_pkrtz(a, b));
}
__device__ __forceinline__ h2v relu2(h2v v) {
    h2v z = {(_Float16)0.0f, (_Float16)0.0f};
    return __builtin_elementwise_max(v, z);
}
__device__ __forceinline__ float fdot2(h2v a, h2v b, float c) {
    return __builtin_amdgcn_fdot2(__builtin_bit_cast(fp16x2, a),
                                  __builtin_bit_cast(fp16x2, b), c, false);
}
__device__ __forceinline__ float sigmoidf_(float x) { return 1.f / (1.f + expf(-x)); }
// uint4 element by unroll-constant index (folds to .x/.y/.z/.w)
__device__ __forceinline__ uint32_t el(const uint4& u, int k) {
    switch (k) { case 0: return u.x; case 1: return u.y; case 2: return u.z; default: return u.w; }
}

// ---------------------------------------------------------------------------
// Kernel 1 (MFMA): C = z @ W for one of {Wo1, We_i, We_j} per block.y.
// r20 version + block (rb==0, m==0) also converts We_e/We2 to packed-f16
// global workspace (SMEM-path weights for the edge kernel).
// pj stored packed-group pj_q[hp>>2][row][hp&3].
// ---------------------------------------------------------------------------
__global__ __launch_bounds__(512) void node_mfma_kernel(
    const float* __restrict__ z,      // (B*N, 128)
    const float* __restrict__ Wo1,    // (128,256)
    const float* __restrict__ bo1,    // (256)
    const float* __restrict__ Wo2,    // (256,1)
    const float* __restrict__ bo2,    // (1)
    const float* __restrict__ We_i,   // (128,256)
    const float* __restrict__ We_j,   // (128,256)
    const float* __restrict__ be1,    // (256)
    const float* __restrict__ We_e,   // (9,256)
    const float* __restrict__ We2,    // (256,1)
    float* __restrict__ organ_out,    // (B*N)
    uint32_t* __restrict__ pi_h,      // (B*N,128) half2 rows, includes +be1
    uint32_t* __restrict__ pj_q,      // (32 groups,1024 rows) uint4-packed
    uint32_t* __restrict__ wee_g,     // (9*128) half2, [d][h2]
    uint32_t* __restrict__ we2_g)     // (128) half2
{
    __shared__ uint32_t Wlds[256][68];     // ~69.6 KiB, f16-pair, [h][d2^swz]
    __shared__ float org_part[32][4];

    const int t    = threadIdx.x;
    const int lane = t & 63;
    const int wave = t >> 6;
    const int rb   = blockIdx.x;           // row-block: rows 32*rb..32*rb+31
    const int m    = blockIdx.y;           // 0 = Wo1/organ, 1 = We_i/pi, 2 = We_j/pj

    const float* __restrict__ W = (m == 0) ? Wo1 : (m == 1) ? We_i : We_j;

    // ---- one block converts We_e/We2 to h2 workspace ----
    if (m == 0 && rb == 0) {
        for (int idx = t; idx < EDGE_DIM * 128; idx += 512) {
            const int d  = idx >> 7;
            const int h2 = idx & 127;
            wee_g[idx] = h2u(pkrtz(We_e[d * 256 + 2 * h2], We_e[d * 256 + 2 * h2 + 1]));
        }
        if (t < 128) we2_g[t] = h2u(pkrtz(We2[2 * t], We2[2 * t + 1]));
    }

    // ---- stage W -> LDS f16, transposed, swizzled ----
    for (int idx = t; idx < 64 * 256; idx += 512) {
        const int d2 = idx >> 8;           // 0..63 (d-pair)
        const int h  = idx & 255;          // coalesced over h
        const float wlo = W[(2 * d2) * 256 + h];
        const float whi = W[(2 * d2 + 1) * 256 + h];
        Wlds[h][d2 ^ ((h & 7) << 3)] = h2u(pkrtz(wlo, whi));
    }

    // ---- A-frags straight from global ----
    const int rt = wave & 1;               // row-tile
    const int cg = wave >> 1;              // col-group (4 tiles of 16)
    const int kg = lane >> 4;              // k-subgroup
    const int row = rb * 32 + rt * 16 + (lane & 15);

    f16x8 A[4];
#pragma unroll
    for (int kt = 0; kt < 4; ++kt) {
        const float4 za = *(const float4*)&z[(size_t)row * 128 + kt * 32 + kg * 8];
        const float4 zb = *(const float4*)&z[(size_t)row * 128 + kt * 32 + kg * 8 + 4];
        H8 a;
        a.v[0] = pkrtz(za.x, za.y); a.v[1] = pkrtz(za.z, za.w);
        a.v[2] = pkrtz(zb.x, zb.y); a.v[3] = pkrtz(zb.z, zb.w);
        A[kt] = __builtin_bit_cast(f16x8, a);
    }

    __syncthreads();

    // ---- MFMA main: 4 col-tiles x 4 k-tiles ----
    f32x4 C[4];
#pragma unroll
    for (int ct = 0; ct < 4; ++ct) {
        const int col = (cg * 4 + ct) * 16 + (lane & 15);
        C[ct] = (f32x4){0.f, 0.f, 0.f, 0.f};
#pragma unroll
        for (int kt = 0; kt < 4; ++kt) {
            const int d2b = (kt * 16 + kg * 4) ^ ((col & 7) << 3);
            const uint4 w = *(const uint4*)&Wlds[col][d2b];
            H8 b;
            b.v[0] = u2h(w.x); b.v[1] = u2h(w.y);
            b.v[2] = u2h(w.z); b.v[3] = u2h(w.w);
            C[ct] = __builtin_amdgcn_mfma_f32_16x16x32_f16(
                        A[kt], __builtin_bit_cast(f16x8, b), C[ct], 0, 0, 0);
        }
    }

    // ---- epilogues ----
    if (m == 0) {
        float s0 = 0.f, s1 = 0.f, s2 = 0.f, s3 = 0.f;
#pragma unroll
        for (int ct = 0; ct < 4; ++ct) {
            const int col = (cg * 4 + ct) * 16 + (lane & 15);
            const float b1 = bo1[col];
            const float w2 = Wo2[col];
            s0 = fmaf(fmaxf(C[ct].x + b1, 0.f), w2, s0);
            s1 = fmaf(fmaxf(C[ct].y + b1, 0.f), w2, s1);
            s2 = fmaf(fmaxf(C[ct].z + b1, 0.f), w2, s2);
            s3 = fmaf(fmaxf(C[ct].w + b1, 0.f), w2, s3);
        }
#pragma unroll
        for (int off = 1; off <= 8; off <<= 1) {
            s0 += __shfl_xor(s0, off, 64);
            s1 += __shfl_xor(s1, off, 64);
            s2 += __shfl_xor(s2, off, 64);
            s3 += __shfl_xor(s3, off, 64);
        }
        if ((lane & 15) == 0) {
            const int rbase = rt * 16 + kg * 4;
            org_part[rbase + 0][cg] = s0;
            org_part[rbase + 1][cg] = s1;
            org_part[rbase + 2][cg] = s2;
            org_part[rbase + 3][cg] = s3;
        }
        __syncthreads();
        if (t < 32) {
            const float s = org_part[t][0] + org_part[t][1]
                          + org_part[t][2] + org_part[t][3] + bo2[0];
            organ_out[rb * 32 + t] = sigmoidf_(s);
        }
    } else if (m == 1) {
        // pi: row-major [row][hp], +be1
#pragma unroll
        for (int ct = 0; ct < 4; ++ct) {
            const int col = (cg * 4 + ct) * 16 + (lane & 15);
            const float bv = be1[col];
            float v0 = C[ct].x + bv, v1 = C[ct].y + bv;
            float v2 = C[ct].z + bv, v3 = C[ct].w + bv;
            const float p0 = __shfl_xor(v0, 1, 64);
            const float p1 = __shfl_xor(v1, 1, 64);
            const float p2 = __shfl_xor(v2, 1, 64);
            const float p3 = __shfl_xor(v3, 1, 64);
            if (!(lane & 1)) {
                const int hp = col >> 1;
                const size_t gr = (size_t)(rb * 32 + rt * 16 + kg * 4);
                pi_h[(gr + 0) * 128 + hp] = h2u(pkrtz(v0, p0));
                pi_h[(gr + 1) * 128 + hp] = h2u(pkrtz(v1, p1));
                pi_h[(gr + 2) * 128 + hp] = h2u(pkrtz(v2, p2));
                pi_h[(gr + 3) * 128 + hp] = h2u(pkrtz(v3, p3));
            }
        }
    } else {
        // pj: packed-group layout [hp>>2][row][hp&3]
#pragma unroll
        for (int ct = 0; ct < 4; ++ct) {
            const int col = (cg * 4 + ct) * 16 + (lane & 15);
            float v0 = C[ct].x, v1 = C[ct].y, v2 = C[ct].z, v3 = C[ct].w;
            const float p0 = __shfl_xor(v0, 1, 64);
            const float p1 = __shfl_xor(v1, 1, 64);
            const float p2 = __shfl_xor(v2, 1, 64);
            const float p3 = __shfl_xor(v3, 1, 64);
            if (!(lane & 1)) {
                const int hp = col >> 1;
                const size_t gr = (size_t)(rb * 32 + rt * 16 + kg * 4);
                const size_t gbase = (size_t)(hp >> 2) * 1024;
                const int    sub   = hp & 3;
                pj_q[(gbase + gr + 0) * 4 + sub] = h2u(pkrtz(v0, p0));
                pj_q[(gbase + gr + 1) * 4 + sub] = h2u(pkrtz(v1, p1));
                pj_q[(gbase + gr + 2) * 4 + sub] = h2u(pkrtz(v2, p2));
                pj_q[(gbase + gr + 3) * 4 + sub] = h2u(pkrtz(v3, p3));
            }
        }
    }
}

// ---------------------------------------------------------------------------
// Kernel 2: fused edge head — r20 structure (h-split, 8 waves/SIMD, wide pj)
// with weights moved to the SCALAR-MEMORY path.
// Validated wall: wee/we2 broadcast through ANY vector return path (LDS or
// L1) charges 1KB/instr for 16B of data -> ~30us floor (r15-r22 all hit it;
// r21 failed because the index derived from threadIdx so uniformity analysis
// couldn't select s_load). Fix: index = __builtin_amdgcn_readfirstlane(g)
// -> by-construction uniform SGPR -> s_load through the scalar cache (free
// broadcast, weights become SGPR operands of v_pk_*). LDS keeps only pi
// (2 reads/iter). Verification signal: SGPR_Count jumps.
// ---------------------------------------------------------------------------
__global__ __launch_bounds__(256) void edge_kernel(
    const float* __restrict__ E,      // (N,N,9)
    const int*   __restrict__ mask,   // (N,N)
    const uint32_t* __restrict__ wee_g, // (9*128) half2, [d][h2]
    const uint32_t* __restrict__ we2_g, // (128) half2
    const float* __restrict__ be2,    // (1)
    const uint32_t* __restrict__ pi_h,  // (B*N,128) half2 rows
    const uint32_t* __restrict__ pj_q,  // (32,1024) uint4-packed
    float* __restrict__ edge_out)     // (B,N,N)
{
    __shared__ __align__(16) uint32_t pi_s[BATCH][4][128];  // 4 KiB
    __shared__ __align__(16) float    part_s[4][32][2];     // 1 KiB

    const int t    = threadIdx.x;
    const int lane = t & 63;
    const int w    = t >> 6;           // wave: (hh = w>>1, ip = w&1)
    const int bi   = blockIdx.x;
    const int i0   = (bi >> 4) * 4;    // 128 i-blocks
    const int j0   = (bi & 15) * 32;   // 16 j-blocks

    const int jl = lane & 31;
    const int il = 2 * (w & 1) + (lane >> 5);  // local i row 0..3
    const int hh = w >> 1;                     // h-half 0/1

    // ---- stage pi rows: 2 b x 4 i x 128 words = 256 uint4, 1/thread ----
    {
        const int r8 = t >> 5;                // 0..7
        const int c4 = t & 31;                // uint4 col
        const int b  = r8 >> 2;
        const int ii = r8 & 3;
        const uint4 v = *(const uint4*)&pi_h[(size_t)(b * NN + i0 + ii) * 128 + c4 * 4];
        *(uint4*)&pi_s[b][ii][c4 * 4] = v;
    }

    // ---- direct per-lane E registers: 9 floats, stride-36B coalesced ----
    h2v e[9];
    {
        const float* eptr = &E[((size_t)(i0 + il) * NN + j0 + jl) * EDGE_DIM];
        float ef[9];
#pragma unroll
        for (int d = 0; d < EDGE_DIM; ++d) ef[d] = eptr[d];
#pragma unroll
        for (int d = 0; d < EDGE_DIM; ++d) e[d] = pkrtz(ef[d], ef[d]);
    }

    __syncthreads();

    float acc[2] = {0.f, 0.f};   // [b]

    const uint4* __restrict__ pjQ  = (const uint4*)pj_q;   // [32][1024]
    const uint4* __restrict__ weeQ = (const uint4*)wee_g;  // [9][32]
    const uint4* __restrict__ we2Q = (const uint4*)we2_g;  // [32]
    const int jrow = j0 + jl;
    const int g0   = hh * 16;    // this wave's 16 h-groups

#pragma unroll 1
    for (int gg = 0; gg < 16; ++gg) {
        const int g  = g0 + gg;
        // uniform SGPR index -> scalar-path (s_load) weight fetch
        const int gu = __builtin_amdgcn_readfirstlane(g);
        uint4 wee4[EDGE_DIM];
#pragma unroll
        for (int d = 0; d < EDGE_DIM; ++d) wee4[d] = weeQ[d * 32 + gu];
        const uint4 we24 = we2Q[gu];
        // pi (LDS, 2 reads, 2-way broadcast across lane halves)
        const int hc = gu * 4;
        uint4 pi4[2];
        pi4[0] = *(const uint4*)&pi_s[0][il][hc];
        pi4[1] = *(const uint4*)&pi_s[1][il][hc];
        // pj: ONE b128 per batch (512B contiguous per half-wave)
        const uint4 pj40 = pjQ[g * 1024 + jrow];          // b = 0
        const uint4 pj41 = pjQ[g * 1024 + NN + jrow];     // b = 1

#pragma unroll
        for (int k = 0; k < 4; ++k) {
            const h2v w2k = u2h(el(we24, k));
            h2v pe = e[0] * u2h(el(wee4[0], k));
#pragma unroll
            for (int d = 1; d < EDGE_DIM; ++d) pe += e[d] * u2h(el(wee4[d], k));
            h2v t0 = relu2(pe + u2h(el(pj40, k)) + u2h(el(pi4[0], k)));
            acc[0] = fdot2(t0, w2k, acc[0]);
            h2v t1 = relu2(pe + u2h(el(pj41, k)) + u2h(el(pi4[1], k)));
            acc[1] = fdot2(t1, w2k, acc[1]);
        }
    }

    // ---- combine h-halves via LDS; hh=0 waves finish ----
    if (hh == 1) {
        part_s[il][jl][0] = acc[0];
        part_s[il][jl][1] = acc[1];
    }
    __syncthreads();
    if (hh == 0) {
        const float b2 = be2[0];
        const int i = i0 + il;
        const float mv = (float)mask[(size_t)i * NN + j0 + jl];
        const float s0 = acc[0] + part_s[il][jl][0] + b2;
        const float s1 = acc[1] + part_s[il][jl][1] + b2;
        edge_out[((size_t)0 * NN + i) * NN + j0 + jl] = sigmoidf_(s0) * mv;
        edge_out[((size_t)1 * NN + i) * NN + j0 + jl] = sigmoidf_(s1) * mv;
    }
}

extern "C" void kernel_launch(void* const* d_in, const int* in_sizes, int n_in,
                              void* d_out, int out_size, void* d_ws, size_t ws_size,
                              hipStream_t stream) {
    const float* z    = (const float*)d_in[0];   // (B,N,128)
    const float* E    = (const float*)d_in[1];   // (N,N,9)
    const int*   mask = (const int*)  d_in[2];   // (N,N)
    const float* Wo1  = (const float*)d_in[3];
    const float* bo1  = (const float*)d_in[4];
    const float* Wo2  = (const float*)d_in[5];
    const float* bo2  = (const float*)d_in[6];
    const float* We_i = (const float*)d_in[7];
    const float* We_j = (const float*)d_in[8];
    const float* We_e = (const float*)d_in[9];
    const float* be1  = (const float*)d_in[10];
    const float* We2  = (const float*)d_in[11];
    const float* be2  = (const float*)d_in[12];

    float* out_organ = (float*)d_out;                 // (B,N) = 1024
    float* out_edge  = out_organ + BATCH * NN;        // (B,N,N)

    uint32_t* pi_h  = (uint32_t*)d_ws;                        // (B*N,128) half2
    uint32_t* pj_q  = pi_h + (size_t)BATCH * NN * (HIDDEN/2); // (32,1024) uint4-packed
    uint32_t* wee_g = pj_q + (size_t)BATCH * NN * (HIDDEN/2); // (9*128) half2
    uint32_t* we2_g = wee_g + EDGE_DIM * 128;                 // (128) half2

    hipLaunchKernelGGL(node_mfma_kernel,
                       dim3(32, 3), dim3(512), 0, stream,
                       z, Wo1, bo1, Wo2, bo2, We_i, We_j, be1, We_e, We2,
                       out_organ, pi_h, pj_q, wee_g, we2_g);

    hipLaunchKernelGGL(edge_kernel,
                       dim3(128 * 16), dim3(256), 0, stream,
                       E, mask, wee_g, we2_g, be2, pi_h, pj_q, out_edge);
}

// Round 24
// 33.817 us; speedup vs baseline: 1.7291x; 1.0137x over previous
//
#include <hip/hip_runtime.h>
#include <math.h>
#include <stdint.h>

#define D_MODEL 128
#define EDGE_DIM 9
#define HIDDEN 256
#define BATCH 2
#define NN 512

typedef _Float16 h2v    __attribute__((ext_vector_type(2)));
typedef __fp16   fp16x2 __attribute__((ext_vector_type(2)));
typedef _Float16 f16x8  __attribute__((ext_vector_type(8)));
typedef float    f32x4  __attribute__((ext_vector_type(4)));

struct H8 { h2v v[4]; };   // 16B = one MFMA A/B fragment

__device__ __forceinline__ uint32_t h2u(h2v v) { return __builtin_bit_cast(uint32_t, v); }
__device__ __forceinline__ h2v u2h(uint32_t u) { return __builtin_bit_cast(h2v, u); }
__device__ __forceinline__ h2v pkrtz(float a, float b) {
    return __builtin_bit_cast(h2v, __builtin_amdgcn_cvt_pkrtz(a, b));
}
__device__ __forceinline__ h2v relu2(h2v v) {
    h2v z = {(_Float16)0.0f, (_Float16)0.0f};
    return __builtin_elementwise_max(v, z);
}
__device__ __forceinline__ float fdot2(h2v a, h2v b, float c) {
    return __builtin_amdgcn_fdot2(__builtin_bit_cast(fp16x2, a),
                                  __builtin_bit_cast(fp16x2, b), c, false);
}
__device__ __forceinline__ float sigmoidf_(float x) { return 1.f / (1.f + expf(-x)); }
// uint4 element by unroll-constant index (folds to .x/.y/.z/.w)
__device__ __forceinline__ uint32_t el(const uint4& u, int k) {
    switch (k) { case 0: return u.x; case 1: return u.y; case 2: return u.z; default: return u.w; }
}

// ---------------------------------------------------------------------------
// Kernel 1 (MFMA): C = z @ W for one of {Wo1, We_i, We_j} per block.y.
// (Identical to round 23.)
// ---------------------------------------------------------------------------
__global__ __launch_bounds__(512) void node_mfma_kernel(
    const float* __restrict__ z,      // (B*N, 128)
    const float* __restrict__ Wo1,    // (128,256)
    const float* __restrict__ bo1,    // (256)
    const float* __restrict__ Wo2,    // (256,1)
    const float* __restrict__ bo2,    // (1)
    const float* __restrict__ We_i,   // (128,256)
    const float* __restrict__ We_j,   // (128,256)
    const float* __restrict__ be1,    // (256)
    const float* __restrict__ We_e,   // (9,256)
    const float* __restrict__ We2,    // (256,1)
    float* __restrict__ organ_out,    // (B*N)
    uint32_t* __restrict__ pi_h,      // (B*N,128) half2 rows, includes +be1
    uint32_t* __restrict__ pj_q,      // (32 groups,1024 rows) uint4-packed
    uint32_t* __restrict__ wee_g,     // (9*128) half2, [d][h2]
    uint32_t* __restrict__ we2_g)     // (128) half2
{
    __shared__ uint32_t Wlds[256][68];     // ~69.6 KiB, f16-pair, [h][d2^swz]
    __shared__ float org_part[32][4];

    const int t    = threadIdx.x;
    const int lane = t & 63;
    const int wave = t >> 6;
    const int rb   = blockIdx.x;           // row-block: rows 32*rb..32*rb+31
    const int m    = blockIdx.y;           // 0 = Wo1/organ, 1 = We_i/pi, 2 = We_j/pj

    const float* __restrict__ W = (m == 0) ? Wo1 : (m == 1) ? We_i : We_j;

    // ---- one block converts We_e/We2 to h2 workspace ----
    if (m == 0 && rb == 0) {
        for (int idx = t; idx < EDGE_DIM * 128; idx += 512) {
            const int d  = idx >> 7;
            const int h2 = idx & 127;
            wee_g[idx] = h2u(pkrtz(We_e[d * 256 + 2 * h2], We_e[d * 256 + 2 * h2 + 1]));
        }
        if (t < 128) we2_g[t] = h2u(pkrtz(We2[2 * t], We2[2 * t + 1]));
    }

    // ---- stage W -> LDS f16, transposed, swizzled ----
    for (int idx = t; idx < 64 * 256; idx += 512) {
        const int d2 = idx >> 8;           // 0..63 (d-pair)
        const int h  = idx & 255;          // coalesced over h
        const float wlo = W[(2 * d2) * 256 + h];
        const float whi = W[(2 * d2 + 1) * 256 + h];
        Wlds[h][d2 ^ ((h & 7) << 3)] = h2u(pkrtz(wlo, whi));
    }

    // ---- A-frags straight from global ----
    const int rt = wave & 1;               // row-tile
    const int cg = wave >> 1;              // col-group (4 tiles of 16)
    const int kg = lane >> 4;              // k-subgroup
    const int row = rb * 32 + rt * 16 + (lane & 15);

    f16x8 A[4];
#pragma unroll
    for (int kt = 0; kt < 4; ++kt) {
        const float4 za = *(const float4*)&z[(size_t)row * 128 + kt * 32 + kg * 8];
        const float4 zb = *(const float4*)&z[(size_t)row * 128 + kt * 32 + kg * 8 + 4];
        H8 a;
        a.v[0] = pkrtz(za.x, za.y); a.v[1] = pkrtz(za.z, za.w);
        a.v[2] = pkrtz(zb.x, zb.y); a.v[3] = pkrtz(zb.z, zb.w);
        A[kt] = __builtin_bit_cast(f16x8, a);
    }

    __syncthreads();

    // ---- MFMA main: 4 col-tiles x 4 k-tiles ----
    f32x4 C[4];
#pragma unroll
    for (int ct = 0; ct < 4; ++ct) {
        const int col = (cg * 4 + ct) * 16 + (lane & 15);
        C[ct] = (f32x4){0.f, 0.f, 0.f, 0.f};
#pragma unroll
        for (int kt = 0; kt < 4; ++kt) {
            const int d2b = (kt * 16 + kg * 4) ^ ((col & 7) << 3);
            const uint4 w = *(const uint4*)&Wlds[col][d2b];
            H8 b;
            b.v[0] = u2h(w.x); b.v[1] = u2h(w.y);
            b.v[2] = u2h(w.z); b.v[3] = u2h(w.w);
            C[ct] = __builtin_amdgcn_mfma_f32_16x16x32_f16(
                        A[kt], __builtin_bit_cast(f16x8, b), C[ct], 0, 0, 0);
        }
    }

    // ---- epilogues ----
    if (m == 0) {
        float s0 = 0.f, s1 = 0.f, s2 = 0.f, s3 = 0.f;
#pragma unroll
        for (int ct = 0; ct < 4; ++ct) {
            const int col = (cg * 4 + ct) * 16 + (lane & 15);
            const float b1 = bo1[col];
            const float w2 = Wo2[col];
            s0 = fmaf(fmaxf(C[ct].x + b1, 0.f), w2, s0);
            s1 = fmaf(fmaxf(C[ct].y + b1, 0.f), w2, s1);
            s2 = fmaf(fmaxf(C[ct].z + b1, 0.f), w2, s2);
            s3 = fmaf(fmaxf(C[ct].w + b1, 0.f), w2, s3);
        }
#pragma unroll
        for (int off = 1; off <= 8; off <<= 1) {
            s0 += __shfl_xor(s0, off, 64);
            s1 += __shfl_xor(s1, off, 64);
            s2 += __shfl_xor(s2, off, 64);
            s3 += __shfl_xor(s3, off, 64);
        }
        if ((lane & 15) == 0) {
            const int rbase = rt * 16 + kg * 4;
            org_part[rbase + 0][cg] = s0;
            org_part[rbase + 1][cg] = s1;
            org_part[rbase + 2][cg] = s2;
            org_part[rbase + 3][cg] = s3;
        }
        __syncthreads();
        if (t < 32) {
            const float s = org_part[t][0] + org_part[t][1]
                          + org_part[t][2] + org_part[t][3] + bo2[0];
            organ_out[rb * 32 + t] = sigmoidf_(s);
        }
    } else if (m == 1) {
        // pi: row-major [row][hp], +be1
#pragma unroll
        for (int ct = 0; ct < 4; ++ct) {
            const int col = (cg * 4 + ct) * 16 + (lane & 15);
            const float bv = be1[col];
            float v0 = C[ct].x + bv, v1 = C[ct].y + bv;
            float v2 = C[ct].z + bv, v3 = C[ct].w + bv;
            const float p0 = __shfl_xor(v0, 1, 64);
            const float p1 = __shfl_xor(v1, 1, 64);
            const float p2 = __shfl_xor(v2, 1, 64);
            const float p3 = __shfl_xor(v3, 1, 64);
            if (!(lane & 1)) {
                const int hp = col >> 1;
                const size_t gr = (size_t)(rb * 32 + rt * 16 + kg * 4);
                pi_h[(gr + 0) * 128 + hp] = h2u(pkrtz(v0, p0));
                pi_h[(gr + 1) * 128 + hp] = h2u(pkrtz(v1, p1));
                pi_h[(gr + 2) * 128 + hp] = h2u(pkrtz(v2, p2));
                pi_h[(gr + 3) * 128 + hp] = h2u(pkrtz(v3, p3));
            }
        }
    } else {
        // pj: packed-group layout [hp>>2][row][hp&3]
#pragma unroll
        for (int ct = 0; ct < 4; ++ct) {
            const int col = (cg * 4 + ct) * 16 + (lane & 15);
            float v0 = C[ct].x, v1 = C[ct].y, v2 = C[ct].z, v3 = C[ct].w;
            const float p0 = __shfl_xor(v0, 1, 64);
            const float p1 = __shfl_xor(v1, 1, 64);
            const float p2 = __shfl_xor(v2, 1, 64);
            const float p3 = __shfl_xor(v3, 1, 64);
            if (!(lane & 1)) {
                const int hp = col >> 1;
                const size_t gr = (size_t)(rb * 32 + rt * 16 + kg * 4);
                const size_t gbase = (size_t)(hp >> 2) * 1024;
                const int    sub   = hp & 3;
                pj_q[(gbase + gr + 0) * 4 + sub] = h2u(pkrtz(v0, p0));
                pj_q[(gbase + gr + 1) * 4 + sub] = h2u(pkrtz(v1, p1));
                pj_q[(gbase + gr + 2) * 4 + sub] = h2u(pkrtz(v2, p2));
                pj_q[(gbase + gr + 3) * 4 + sub] = h2u(pkrtz(v3, p3));
            }
        }
    }
}

// ---------------------------------------------------------------------------
// Kernel 2: fused edge head — r23 (h-split, 8 waves/SIMD, wide pj, SMEM-path
// weights via readfirstlane) with the hc-loop at #pragma unroll 2.
// r23 removed nearly all per-iteration memory-pipe pressure yet edge stays
// ~27us vs a 7.3us VALU floor -> the residual stall is the unroll-1 lockstep
// (loads -> compute -> drain lgkm/vmcnt every 16 iterations with zero
// cross-iteration overlap; the ~72cy of load-independent pe VALU can't cover
// the ~200-400cy pj/s_load latency). unroll 2 = BOUNDED software pipeline:
// the compiler may interleave iteration g+1's loads under iteration g's
// compute with bounded live-range growth (est. +16-20 VGPR, target <=64 to
// keep 8 waves/SIMD; default-heuristic unbounded unroll is what spilled in
// r13/r14).
// ---------------------------------------------------------------------------
__global__ __launch_bounds__(256) void edge_kernel(
    const float* __restrict__ E,      // (N,N,9)
    const int*   __restrict__ mask,   // (N,N)
    const uint32_t* __restrict__ wee_g, // (9*128) half2, [d][h2]
    const uint32_t* __restrict__ we2_g, // (128) half2
    const float* __restrict__ be2,    // (1)
    const uint32_t* __restrict__ pi_h,  // (B*N,128) half2 rows
    const uint32_t* __restrict__ pj_q,  // (32,1024) uint4-packed
    float* __restrict__ edge_out)     // (B,N,N)
{
    __shared__ __align__(16) uint32_t pi_s[BATCH][4][128];  // 4 KiB
    __shared__ __align__(16) float    part_s[4][32][2];     // 1 KiB

    const int t    = threadIdx.x;
    const int lane = t & 63;
    const int w    = t >> 6;           // wave: (hh = w>>1, ip = w&1)
    const int bi   = blockIdx.x;
    const int i0   = (bi >> 4) * 4;    // 128 i-blocks
    const int j0   = (bi & 15) * 32;   // 16 j-blocks

    const int jl = lane & 31;
    const int il = 2 * (w & 1) + (lane >> 5);  // local i row 0..3
    const int hh = w >> 1;                     // h-half 0/1

    // ---- stage pi rows: 2 b x 4 i x 128 words = 256 uint4, 1/thread ----
    {
        const int r8 = t >> 5;                // 0..7
        const int c4 = t & 31;                // uint4 col
        const int b  = r8 >> 2;
        const int ii = r8 & 3;
        const uint4 v = *(const uint4*)&pi_h[(size_t)(b * NN + i0 + ii) * 128 + c4 * 4];
        *(uint4*)&pi_s[b][ii][c4 * 4] = v;
    }

    // ---- direct per-lane E registers: 9 floats, stride-36B coalesced ----
    h2v e[9];
    {
        const float* eptr = &E[((size_t)(i0 + il) * NN + j0 + jl) * EDGE_DIM];
        float ef[9];
#pragma unroll
        for (int d = 0; d < EDGE_DIM; ++d) ef[d] = eptr[d];
#pragma unroll
        for (int d = 0; d < EDGE_DIM; ++d) e[d] = pkrtz(ef[d], ef[d]);
    }

    __syncthreads();

    float acc[2] = {0.f, 0.f};   // [b]

    const uint4* __restrict__ pjQ  = (const uint4*)pj_q;   // [32][1024]
    const uint4* __restrict__ weeQ = (const uint4*)wee_g;  // [9][32]
    const uint4* __restrict__ we2Q = (const uint4*)we2_g;  // [32]
    const int jrow = j0 + jl;
    const int g0   = hh * 16;    // this wave's 16 h-groups

#pragma unroll 2
    for (int gg = 0; gg < 16; ++gg) {
        const int g  = g0 + gg;
        // uniform SGPR index -> scalar-path (s_load) weight fetch
        const int gu = __builtin_amdgcn_readfirstlane(g);
        uint4 wee4[EDGE_DIM];
#pragma unroll
        for (int d = 0; d < EDGE_DIM; ++d) wee4[d] = weeQ[d * 32 + gu];
        const uint4 we24 = we2Q[gu];
        // pi (LDS, 2 reads, 2-way broadcast across lane halves)
        const int hc = gu * 4;
        uint4 pi4[2];
        pi4[0] = *(const uint4*)&pi_s[0][il][hc];
        pi4[1] = *(const uint4*)&pi_s[1][il][hc];
        // pj: ONE b128 per batch (512B contiguous per half-wave)
        const uint4 pj40 = pjQ[g * 1024 + jrow];          // b = 0
        const uint4 pj41 = pjQ[g * 1024 + NN + jrow];     // b = 1

#pragma unroll
        for (int k = 0; k < 4; ++k) {
            const h2v w2k = u2h(el(we24, k));
            h2v pe = e[0] * u2h(el(wee4[0], k));
#pragma unroll
            for (int d = 1; d < EDGE_DIM; ++d) pe += e[d] * u2h(el(wee4[d], k));
            h2v t0 = relu2(pe + u2h(el(pj40, k)) + u2h(el(pi4[0], k)));
            acc[0] = fdot2(t0, w2k, acc[0]);
            h2v t1 = relu2(pe + u2h(el(pj41, k)) + u2h(el(pi4[1], k)));
            acc[1] = fdot2(t1, w2k, acc[1]);
        }
    }

    // ---- combine h-halves via LDS; hh=0 waves finish ----
    if (hh == 1) {
        part_s[il][jl][0] = acc[0];
        part_s[il][jl][1] = acc[1];
    }
    __syncthreads();
    if (hh == 0) {
        const float b2 = be2[0];
        const int i = i0 + il;
        const float mv = (float)mask[(size_t)i * NN + j0 + jl];
        const float s0 = acc[0] + part_s[il][jl][0] + b2;
        const float s1 = acc[1] + part_s[il][jl][1] + b2;
        edge_out[((size_t)0 * NN + i) * NN + j0 + jl] = sigmoidf_(s0) * mv;
        edge_out[((size_t)1 * NN + i) * NN + j0 + jl] = sigmoidf_(s1) * mv;
    }
}

extern "C" void kernel_launch(void* const* d_in, const int* in_sizes, int n_in,
                              void* d_out, int out_size, void* d_ws, size_t ws_size,
                              hipStream_t stream) {
    const float* z    = (const float*)d_in[0];   // (B,N,128)
    const float* E    = (const float*)d_in[1];   // (N,N,9)
    const int*   mask = (const int*)  d_in[2];   // (N,N)
    const float* Wo1  = (const float*)d_in[3];
    const float* bo1  = (const float*)d_in[4];
    const float* Wo2  = (const float*)d_in[5];
    const float* bo2  = (const float*)d_in[6];
    const float* We_i = (const float*)d_in[7];
    const float* We_j = (const float*)d_in[8];
    const float* We_e = (const float*)d_in[9];
    const float* be1  = (const float*)d_in[10];
    const float* We2  = (const float*)d_in[11];
    const float* be2  = (const float*)d_in[12];

    float* out_organ = (float*)d_out;                 // (B,N) = 1024
    float* out_edge  = out_organ + BATCH * NN;        // (B,N,N)

    uint32_t* pi_h  = (uint32_t*)d_ws;                        // (B*N,128) half2
    uint32_t* pj_q  = pi_h + (size_t)BATCH * NN * (HIDDEN/2); // (32,1024) uint4-packed
    uint32_t* wee_g = pj_q + (size_t)BATCH * NN * (HIDDEN/2); // (9*128) half2
    uint32_t* we2_g = wee_g + EDGE_DIM * 128;                 // (128) half2

    hipLaunchKernelGGL(node_mfma_kernel,
                       dim3(32, 3), dim3(512), 0, stream,
                       z, Wo1, bo1, Wo2, bo2, We_i, We_j, be1, We_e, We2,
                       out_organ, pi_h, pj_q, wee_g, we2_g);

    hipLaunchKernelGGL(edge_kernel,
                       dim3(128 * 16), dim3(256), 0, stream,
                       E, mask, wee_g, we2_g, be2, pi_h, pj_q, out_edge);
}